// Round 13
// baseline (261.592 us; speedup 1.0000x reference)
//
#include <hip/hip_runtime.h>
#include <stdint.h>

typedef float  f32x4   __attribute__((ext_vector_type(4)));
typedef float  float4v __attribute__((ext_vector_type(4)));
typedef short  short4v __attribute__((ext_vector_type(4)));
typedef short  short8v __attribute__((ext_vector_type(8)));
typedef __bf16 bf16x8  __attribute__((ext_vector_type(8)));

static __device__ __forceinline__ short f2bf(float f) {
  unsigned u = __builtin_bit_cast(unsigned, f);
  u += 0x7FFFu + ((u >> 16) & 1u);
  return (short)(u >> 16);
}

static __device__ __forceinline__ f32x4 mfma16(short8v a, short8v b, f32x4 c) {
  return __builtin_amdgcn_mfma_f32_16x16x32_bf16(
      __builtin_bit_cast(bf16x8, a), __builtin_bit_cast(bf16x8, b), c, 0, 0, 0);
}

static __device__ __forceinline__ short8v cat44(short4v a, short4v b) {
  short8v r;
  r[0] = a[0]; r[1] = a[1]; r[2] = a[2]; r[3] = a[3];
  r[4] = b[0]; r[5] = b[1]; r[6] = b[2]; r[7] = b[3];
  return r;
}

// Prelude A: convert qkv_w (384x128) and proj_w (128x128) f32 -> bf16.
__global__ void cvt_weights_kernel(const float* __restrict__ qkv_w,
                                   const float* __restrict__ proj_w,
                                   short* __restrict__ wq, short* __restrict__ wp) {
  int i = blockIdx.x * 256 + threadIdx.x;   // grid = 192 blocks -> 49152
  wq[i] = f2bf(qkv_w[i]);
  if (i < 16384) wp[i] = f2bf(proj_w[i]);
}

// Prelude B: combined bias+mask table laid out as the MFMA S-fragment:
// cmb[w(64)][h(4)][qt(4)][i(4)][lane(64)][r(4)] f32  (4 MB)
__global__ void build_cmb_kernel(const float* __restrict__ mask,
                                 const float* __restrict__ bias_table,
                                 float* __restrict__ cmb) {
  int id   = blockIdx.x * 256 + threadIdx.x;   // grid = 1024 blocks
  int lane = id & 63;
  int i    = (id >> 6) & 3;
  int qt   = (id >> 8) & 3;
  int h    = (id >> 10) & 3;
  int w    = id >> 12;
  int q     = qt * 16 + (lane & 15);
  int kbase = i * 16 + ((lane >> 4) << 2);
  f32x4 v;
#pragma unroll
  for (int r = 0; r < 4; ++r) {
    int key = kbase + r;
    float val;
    if (key >= 49) {
      val = -1e30f;
    } else if (q >= 49) {
      val = 0.f;
    } else {
      int qi = q / 7, qj = q - qi * 7;
      int ki = key / 7, kj = key - ki * 7;
      int ridx = (qi - ki + 6) * 13 + (qj - kj + 6);
      val = bias_table[ridx * 4 + h] + mask[w * 2401 + q * 49 + key];
    }
    v[r] = val;
  }
  ((f32x4*)cmb)[id] = v;
}

// Persistent blocks: grid 512 (2/CU), each block processes 8 windows with
// double-buffered x staging (T14: issue next window's global loads before the
// compute phases, LDS-write after). 256 threads = 4 waves; wave = head h,
// all 64 tokens (the R12 in-register structure, 256-VGPR budget).
// LDS 69632 B: xb[2] [64][136] + vtm [4][32][68] + aom [64][136].
// 2 barriers per window.
__global__ __launch_bounds__(256, 2)
void win_attn_kernel(const float* __restrict__ x,
                     const float* __restrict__ qkv_b,
                     const float* __restrict__ proj_b,
                     const short* __restrict__ wq,
                     const short* __restrict__ wp,
                     const float* __restrict__ cmb,
                     float* __restrict__ out) {
  __shared__ __align__(16) short smem[34816];
  // shorts: xb0 [0,8704) xb1 [8704,17408) vtm [17408,26112) aom [26112,34816)
  short* vtm = smem + 17408;
  short* aom = smem + 26112;

  const int tid  = threadIdx.x;
  const int lane = tid & 63;
  const int h    = tid >> 6;    // wave = head
  const int l15  = lane & 15;
  const int lhi  = lane >> 4;
  const int cb   = lhi * 8;
  const int wbase = blockIdx.x * 8;
  const float scale = 0.1767766952966369f;  // 32^-0.5

  // ---- Prologue: zero pad rows 49..63 of both buffers; stage window 0.
  {
    short4v z = {0, 0, 0, 0};
    for (int i = tid; i < 510; i += 256) {
      *(short4v*)&smem[49 * 136 + i * 4]        = z;
      *(short4v*)&smem[8704 + 49 * 136 + i * 4] = z;
    }
    const float* xw = x + (long)wbase * 6272;
#pragma unroll
    for (int k = 0; k < 7; ++k) {
      const int idx = tid + k * 256;
      if (idx < 1568) {
        float4v v = *(const float4v*)&xw[idx * 4];
        short4v s;
        s[0] = f2bf(v[0]); s[1] = f2bf(v[1]); s[2] = f2bf(v[2]); s[3] = f2bf(v[3]);
        *(short4v*)&smem[(idx >> 5) * 136 + ((idx & 31) << 2)] = s;
      }
    }
  }
  __syncthreads();

  int cur = 0;
  for (int wloc = 0; wloc < 8; ++wloc) {
    const int w = wbase + wloc;
    const short* xb = smem + cur * 8704;

    // ---- Prefetch next window's x into registers (HBM latency hides under
    // the compute phases below).
    float4v pf[7];
    const bool havenext = (wloc < 7);
    if (havenext) {
      const float* xwn = x + (long)(w + 1) * 6272;
#pragma unroll
      for (int k = 0; k < 7; ++k) {
        const int idx = tid + k * 256;
        if (idx < 1568) pf[k] = *(const float4v*)&xwn[idx * 4];
      }
    }

    // ---- Phase 1a: Q+K projection (swapped: acc = [wcol][token]).
    short8v qfr[4], kfr[4];
    {
      f32x4 qa[2][4], ka[2][4];   // [nt][jt]
#pragma unroll
      for (int nt = 0; nt < 2; ++nt) {
        const f32x4 bq4 = *(const f32x4*)&qkv_b[h * 32 + nt * 16 + lhi * 4];
        const f32x4 bk4 = *(const f32x4*)&qkv_b[128 + h * 32 + nt * 16 + lhi * 4];
#pragma unroll
        for (int jt = 0; jt < 4; ++jt) { qa[nt][jt] = bq4; ka[nt][jt] = bk4; }
      }
#pragma unroll
      for (int ks = 0; ks < 4; ++ks) {
        short8v a[4];
#pragma unroll
        for (int jt = 0; jt < 4; ++jt)
          a[jt] = *(const short8v*)&xb[(jt * 16 + l15) * 136 + ks * 32 + cb];
#pragma unroll
        for (int nt = 0; nt < 2; ++nt) {
          const short8v bq =
              *(const short8v*)&wq[(h * 32 + nt * 16 + l15) * 128 + ks * 32 + cb];
          const short8v bk =
              *(const short8v*)&wq[(128 + h * 32 + nt * 16 + l15) * 128 + ks * 32 + cb];
#pragma unroll
          for (int jt = 0; jt < 4; ++jt) {
            qa[nt][jt] = mfma16(bq, a[jt], qa[nt][jt]);
            ka[nt][jt] = mfma16(bk, a[jt], ka[nt][jt]);
          }
        }
      }
#pragma unroll
      for (int jt = 0; jt < 4; ++jt) {
        short8v qv, kv;
#pragma unroll
        for (int nt = 0; nt < 2; ++nt)
#pragma unroll
          for (int r = 0; r < 4; ++r) {
            qv[nt * 4 + r] = f2bf(qa[nt][jt][r] * scale);
            kv[nt * 4 + r] = f2bf(ka[nt][jt][r]);
          }
        qfr[jt] = qv;
        kfr[jt] = kv;
      }
    }

    // ---- Phase 1b: V projection (normal), store to OWN vtm slice.
    {
      f32x4 va[2][4];   // [nt][mt]
#pragma unroll
      for (int nt = 0; nt < 2; ++nt) {
        const float vb = qkv_b[256 + h * 32 + nt * 16 + l15];
#pragma unroll
        for (int mt = 0; mt < 4; ++mt) va[nt][mt] = f32x4{vb, vb, vb, vb};
      }
#pragma unroll
      for (int ks = 0; ks < 4; ++ks) {
        short8v a[4];
#pragma unroll
        for (int mt = 0; mt < 4; ++mt)
          a[mt] = *(const short8v*)&xb[(mt * 16 + l15) * 136 + ks * 32 + cb];
#pragma unroll
        for (int nt = 0; nt < 2; ++nt) {
          const short8v bv =
              *(const short8v*)&wq[(256 + h * 32 + nt * 16 + l15) * 128 + ks * 32 + cb];
#pragma unroll
          for (int mt = 0; mt < 4; ++mt)
            va[nt][mt] = mfma16(a[mt], bv, va[nt][mt]);
        }
      }
#pragma unroll
      for (int nt = 0; nt < 2; ++nt)
#pragma unroll
        for (int mt = 0; mt < 4; ++mt) {
          short4v p;
#pragma unroll
          for (int r = 0; r < 4; ++r) p[r] = f2bf(va[nt][mt][r]);
          *(short4v*)&vtm[h * 2176 + (nt * 16 + l15) * 68 + mt * 16 + lhi * 4] = p;
        }
    }
    // vtm slice private to this wave: in-wave ordering only.

    // ---- Phase 2: S = mfma(K,Q)+cmb; in-lane softmax; PV -> aom.
    // (aom free: previous window's proj reads finished before last barrier.)
    {
      const f32x4* cmb4 = (const f32x4*)cmb;
      const long cbase = (long)(w & 63) * 4096 + h * 1024 + lane;

#pragma unroll
      for (int jt = 0; jt < 4; ++jt) {
        f32x4 s[4];
#pragma unroll
        for (int i = 0; i < 4; ++i)
          s[i] = mfma16(kfr[i], qfr[jt], cmb4[cbase + jt * 256 + i * 64]);

        float mx = s[0][0];
#pragma unroll
        for (int i = 0; i < 4; ++i)
#pragma unroll
          for (int r = 0; r < 4; ++r) mx = fmaxf(mx, s[i][r]);
        mx = fmaxf(mx, __shfl_xor(mx, 16));
        mx = fmaxf(mx, __shfl_xor(mx, 32));
        float sum = 0.f;
#pragma unroll
        for (int i = 0; i < 4; ++i)
#pragma unroll
          for (int r = 0; r < 4; ++r) {
            float e = __expf(s[i][r] - mx);
            s[i][r] = e;
            sum += e;
          }
        sum += __shfl_xor(sum, 16);
        sum += __shfl_xor(sum, 32);
        const float inv = 1.f / sum;

        short8v pb[2];
#pragma unroll
        for (int ks = 0; ks < 2; ++ks) {
          short8v pv;
#pragma unroll
          for (int e = 0; e < 4; ++e) pv[e]     = f2bf(s[2 * ks][e] * inv);
#pragma unroll
          for (int e = 0; e < 4; ++e) pv[4 + e] = f2bf(s[2 * ks + 1][e] * inv);
          pb[ks] = pv;
        }

#pragma unroll
        for (int dt = 0; dt < 2; ++dt) {
          f32x4 o = {0.f, 0.f, 0.f, 0.f};
#pragma unroll
          for (int ks = 0; ks < 2; ++ks) {
            const int va = h * 2176 + (dt * 16 + l15) * 68 + ks * 32 + lhi * 4;
            short8v vfr =
                cat44(*(const short4v*)&vtm[va], *(const short4v*)&vtm[va + 16]);
            o = mfma16(vfr, pb[ks], o);
          }
          short4v p;
#pragma unroll
          for (int r = 0; r < 4; ++r) p[r] = f2bf(o[r]);
          *(short4v*)&aom[(jt * 16 + l15) * 136 + h * 32 + dt * 16 + lhi * 4] = p;
        }
      }
    }
    __syncthreads();   // barrier X: aom complete

    // ---- Phase 3: output projection Y = AO @ proj_w^T + proj_b.
    {
      f32x4 po[2][4];   // [nt][mt]
#pragma unroll
      for (int nt = 0; nt < 2; ++nt) {
        const float pbv = proj_b[h * 32 + nt * 16 + l15];
#pragma unroll
        for (int mt = 0; mt < 4; ++mt) po[nt][mt] = f32x4{pbv, pbv, pbv, pbv};
      }
#pragma unroll
      for (int ks = 0; ks < 4; ++ks) {
        short8v p[4];
#pragma unroll
        for (int mt = 0; mt < 4; ++mt)
          p[mt] = *(const short8v*)&aom[(mt * 16 + l15) * 136 + ks * 32 + cb];
#pragma unroll
        for (int nt = 0; nt < 2; ++nt) {
          const short8v wfr =
              *(const short8v*)&wp[(h * 32 + nt * 16 + l15) * 128 + ks * 32 + cb];
#pragma unroll
          for (int mt = 0; mt < 4; ++mt)
            po[nt][mt] = mfma16(p[mt], wfr, po[nt][mt]);
        }
      }
      float* outw = out + (long)w * 6272;
#pragma unroll
      for (int nt = 0; nt < 2; ++nt) {
        const int ncol = h * 32 + nt * 16 + l15;
#pragma unroll
        for (int mt = 0; mt < 4; ++mt)
#pragma unroll
          for (int r = 0; r < 4; ++r) {
            const int tok = mt * 16 + lhi * 4 + r;
            if (tok < 49) outw[tok * 128 + ncol] = po[nt][mt][r];
          }
      }
    }

    // ---- Stage-write: prefetched x -> other LDS buffer (its last readers
    // finished a full window ago).
    if (havenext) {
      short* dst = smem + (cur ^ 1) * 8704;
#pragma unroll
      for (int k = 0; k < 7; ++k) {
        const int idx = tid + k * 256;
        if (idx < 1568) {
          short4v s;
          s[0] = f2bf(pf[k][0]); s[1] = f2bf(pf[k][1]);
          s[2] = f2bf(pf[k][2]); s[3] = f2bf(pf[k][3]);
          *(short4v*)&dst[(idx >> 5) * 136 + ((idx & 31) << 2)] = s;
        }
      }
    }
    __syncthreads();   // barrier Y: xb[next] ready; aom free for next window
    cur ^= 1;
  }
}

extern "C" void kernel_launch(void* const* d_in, const int* in_sizes, int n_in,
                              void* d_out, int out_size, void* d_ws, size_t ws_size,
                              hipStream_t stream) {
  const float* x          = (const float*)d_in[0];
  const float* mask       = (const float*)d_in[1];
  const float* qkv_w      = (const float*)d_in[2];
  const float* qkv_b      = (const float*)d_in[3];
  const float* proj_w     = (const float*)d_in[4];
  const float* proj_b     = (const float*)d_in[5];
  const float* bias_table = (const float*)d_in[6];

  short* wq  = (short*)d_ws;                         // 384*128 bf16 (98304 B)
  short* wp  = wq + 49152;                           // 128*128 bf16 (32768 B)
  float* cmb = (float*)((char*)d_ws + 131072);       // 4 MB combined bias+mask

  cvt_weights_kernel<<<dim3(192), dim3(256), 0, stream>>>(qkv_w, proj_w, wq, wp);
  build_cmb_kernel<<<dim3(1024), dim3(256), 0, stream>>>(mask, bias_table, cmb);
  win_attn_kernel<<<dim3(512), dim3(256), 0, stream>>>(
      x, qkv_b, proj_b, wq, wp, cmb, (float*)d_out);
}

// Round 14
// 202.592 us; speedup vs baseline: 1.2912x; 1.2912x over previous
//
#include <hip/hip_runtime.h>
#include <stdint.h>

typedef float  f32x4   __attribute__((ext_vector_type(4)));
typedef float  float4v __attribute__((ext_vector_type(4)));
typedef short  short4v __attribute__((ext_vector_type(4)));
typedef short  short8v __attribute__((ext_vector_type(8)));
typedef __bf16 bf16x8  __attribute__((ext_vector_type(8)));

static __device__ __forceinline__ short f2bf(float f) {
  unsigned u = __builtin_bit_cast(unsigned, f);
  u += 0x7FFFu + ((u >> 16) & 1u);
  return (short)(u >> 16);
}

static __device__ __forceinline__ f32x4 mfma16(short8v a, short8v b, f32x4 c) {
  return __builtin_amdgcn_mfma_f32_16x16x32_bf16(
      __builtin_bit_cast(bf16x8, a), __builtin_bit_cast(bf16x8, b), c, 0, 0, 0);
}

static __device__ __forceinline__ short8v cat44(short4v a, short4v b) {
  short8v r;
  r[0] = a[0]; r[1] = a[1]; r[2] = a[2]; r[3] = a[3];
  r[4] = b[0]; r[5] = b[1]; r[6] = b[2]; r[7] = b[3];
  return r;
}

// Prelude A: convert qkv_w (384x128) and proj_w (128x128) f32 -> bf16.
__global__ void cvt_weights_kernel(const float* __restrict__ qkv_w,
                                   const float* __restrict__ proj_w,
                                   short* __restrict__ wq, short* __restrict__ wp) {
  int i = blockIdx.x * 256 + threadIdx.x;   // grid = 192 blocks -> 49152
  wq[i] = f2bf(qkv_w[i]);
  if (i < 16384) wp[i] = f2bf(proj_w[i]);
}

// Prelude B: combined bias+mask table laid out as the MFMA S-fragment:
// cmb[w(64)][h(4)][qt(4)][i(4)][lane(64)][r(4)] f32  (4 MB)
__global__ void build_cmb_kernel(const float* __restrict__ mask,
                                 const float* __restrict__ bias_table,
                                 float* __restrict__ cmb) {
  int id   = blockIdx.x * 256 + threadIdx.x;   // grid = 1024 blocks
  int lane = id & 63;
  int i    = (id >> 6) & 3;
  int qt   = (id >> 8) & 3;
  int h    = (id >> 10) & 3;
  int w    = id >> 12;
  int q     = qt * 16 + (lane & 15);
  int kbase = i * 16 + ((lane >> 4) << 2);
  f32x4 v;
#pragma unroll
  for (int r = 0; r < 4; ++r) {
    int key = kbase + r;
    float val;
    if (key >= 49) {
      val = -1e30f;
    } else if (q >= 49) {
      val = 0.f;
    } else {
      int qi = q / 7, qj = q - qi * 7;
      int ki = key / 7, kj = key - ki * 7;
      int ridx = (qi - ki + 6) * 13 + (qj - kj + 6);
      val = bias_table[ridx * 4 + h] + mask[w * 2401 + q * 49 + key];
    }
    v[r] = val;
  }
  ((f32x4*)cmb)[id] = v;
}

// One block = TWO windows (b and b+2048, same cmb rows since 2048%64==0).
// 256 threads = 4 waves; wave = head h, all 64 tokens of both windows,
// A/B explicitly interleaved in program order (waves are in-order: this is
// the only way to double per-wave MLP). Weight/cmb fragments shared A<->B.
// LDS 69632 B: xbA/xbB [64][136] (aliased by aomA/aomB) + vtmA/vtmB.
// 3 barriers per block (= 1.5 per window).
__global__ __launch_bounds__(256, 2)
void win_attn_kernel(const float* __restrict__ x,
                     const float* __restrict__ qkv_b,
                     const float* __restrict__ proj_b,
                     const short* __restrict__ wq,
                     const short* __restrict__ wp,
                     const float* __restrict__ cmb,
                     float* __restrict__ out) {
  __shared__ __align__(16) short smem[34816];
  short* xbA  = smem;              // [64][136]
  short* xbB  = smem + 8704;       // [64][136]
  short* vtmA = smem + 17408;      // [4][32][68]
  short* vtmB = smem + 26112;      // [4][32][68]
  short* aomA = smem;              // alias xbA after B2
  short* aomB = smem + 8704;       // alias xbB after B2

  const int tid  = threadIdx.x;
  const int lane = tid & 63;
  const int h    = tid >> 6;    // wave = head
  const int l15  = lane & 15;
  const int lhi  = lane >> 4;
  const int cb   = lhi * 8;
  const int wA   = blockIdx.x;
  const int wB   = blockIdx.x + 2048;
  const float scale = 0.1767766952966369f;  // 32^-0.5

  // ---- Phase 0: stage both windows' x -> bf16 LDS, zero pad rows 49..63
  {
    short4v z = {0, 0, 0, 0};
    for (int i = tid; i < 510; i += 256) {
      *(short4v*)&xbA[49 * 136 + i * 4] = z;
      *(short4v*)&xbB[49 * 136 + i * 4] = z;
    }
    const float* xwA = x + (long)wA * 6272;
    const float* xwB = x + (long)wB * 6272;
    for (int idx = tid; idx < 1568; idx += 256) {
      const int m  = idx >> 5;
      const int c0 = (idx & 31) << 2;
      float4v vA = *(const float4v*)&xwA[m * 128 + c0];
      float4v vB = *(const float4v*)&xwB[m * 128 + c0];
      short4v sA, sB;
#pragma unroll
      for (int r = 0; r < 4; ++r) { sA[r] = f2bf(vA[r]); sB[r] = f2bf(vB[r]); }
      *(short4v*)&xbA[m * 136 + c0] = sA;
      *(short4v*)&xbB[m * 136 + c0] = sB;
    }
  }
  __syncthreads();   // B1

  // ---- Phase 1a: Q+K projection for BOTH windows (swapped orientation).
  short8v qfrA[4], kfrA[4], qfrB[4], kfrB[4];
  {
    f32x4 qaA[2][4], kaA[2][4], qaB[2][4], kaB[2][4];   // [nt][jt]
#pragma unroll
    for (int nt = 0; nt < 2; ++nt) {
      const f32x4 bq4 = *(const f32x4*)&qkv_b[h * 32 + nt * 16 + lhi * 4];
      const f32x4 bk4 = *(const f32x4*)&qkv_b[128 + h * 32 + nt * 16 + lhi * 4];
#pragma unroll
      for (int jt = 0; jt < 4; ++jt) {
        qaA[nt][jt] = bq4; kaA[nt][jt] = bk4;
        qaB[nt][jt] = bq4; kaB[nt][jt] = bk4;
      }
    }
#pragma unroll
    for (int ks = 0; ks < 4; ++ks) {
      short8v aA[4], aB[4];
#pragma unroll
      for (int jt = 0; jt < 4; ++jt) {
        aA[jt] = *(const short8v*)&xbA[(jt * 16 + l15) * 136 + ks * 32 + cb];
        aB[jt] = *(const short8v*)&xbB[(jt * 16 + l15) * 136 + ks * 32 + cb];
      }
#pragma unroll
      for (int nt = 0; nt < 2; ++nt) {
        const short8v bq =
            *(const short8v*)&wq[(h * 32 + nt * 16 + l15) * 128 + ks * 32 + cb];
        const short8v bk =
            *(const short8v*)&wq[(128 + h * 32 + nt * 16 + l15) * 128 + ks * 32 + cb];
#pragma unroll
        for (int jt = 0; jt < 4; ++jt) {
          qaA[nt][jt] = mfma16(bq, aA[jt], qaA[nt][jt]);
          qaB[nt][jt] = mfma16(bq, aB[jt], qaB[nt][jt]);
          kaA[nt][jt] = mfma16(bk, aA[jt], kaA[nt][jt]);
          kaB[nt][jt] = mfma16(bk, aB[jt], kaB[nt][jt]);
        }
      }
    }
#pragma unroll
    for (int jt = 0; jt < 4; ++jt) {
      short8v qvA, kvA, qvB, kvB;
#pragma unroll
      for (int nt = 0; nt < 2; ++nt)
#pragma unroll
        for (int r = 0; r < 4; ++r) {
          qvA[nt * 4 + r] = f2bf(qaA[nt][jt][r] * scale);
          kvA[nt * 4 + r] = f2bf(kaA[nt][jt][r]);
          qvB[nt * 4 + r] = f2bf(qaB[nt][jt][r] * scale);
          kvB[nt * 4 + r] = f2bf(kaB[nt][jt][r]);
        }
      qfrA[jt] = qvA; kfrA[jt] = kvA;
      qfrB[jt] = qvB; kfrB[jt] = kvB;
    }
  }

  // ---- Phase 1b: V projection for BOTH windows, store to own vtm slices.
  {
    f32x4 vaA[2][4], vaB[2][4];   // [nt][mt]
#pragma unroll
    for (int nt = 0; nt < 2; ++nt) {
      const float vb = qkv_b[256 + h * 32 + nt * 16 + l15];
#pragma unroll
      for (int mt = 0; mt < 4; ++mt) {
        vaA[nt][mt] = f32x4{vb, vb, vb, vb};
        vaB[nt][mt] = vaA[nt][mt];
      }
    }
#pragma unroll
    for (int ks = 0; ks < 4; ++ks) {
      short8v aA[4], aB[4];
#pragma unroll
      for (int mt = 0; mt < 4; ++mt) {
        aA[mt] = *(const short8v*)&xbA[(mt * 16 + l15) * 136 + ks * 32 + cb];
        aB[mt] = *(const short8v*)&xbB[(mt * 16 + l15) * 136 + ks * 32 + cb];
      }
#pragma unroll
      for (int nt = 0; nt < 2; ++nt) {
        const short8v bv =
            *(const short8v*)&wq[(256 + h * 32 + nt * 16 + l15) * 128 + ks * 32 + cb];
#pragma unroll
        for (int mt = 0; mt < 4; ++mt) {
          vaA[nt][mt] = mfma16(aA[mt], bv, vaA[nt][mt]);
          vaB[nt][mt] = mfma16(aB[mt], bv, vaB[nt][mt]);
        }
      }
    }
#pragma unroll
    for (int nt = 0; nt < 2; ++nt)
#pragma unroll
      for (int mt = 0; mt < 4; ++mt) {
        short4v pA, pB;
#pragma unroll
        for (int r = 0; r < 4; ++r) {
          pA[r] = f2bf(vaA[nt][mt][r]);
          pB[r] = f2bf(vaB[nt][mt][r]);
        }
        *(short4v*)&vtmA[h * 2176 + (nt * 16 + l15) * 68 + mt * 16 + lhi * 4] = pA;
        *(short4v*)&vtmB[h * 2176 + (nt * 16 + l15) * 68 + mt * 16 + lhi * 4] = pB;
      }
  }
  // vtm slices private to this wave: in-wave lgkmcnt ordering suffices.

  // ---- Phase 2: S = mfma(K,Q)+cmb (cmb fragment SHARED A/B); softmax; PV.
  f32x4 oA[2][4], oB[2][4];    // [dt][jt]
#pragma unroll
  for (int dt = 0; dt < 2; ++dt)
#pragma unroll
    for (int jt = 0; jt < 4; ++jt) {
      oA[dt][jt] = f32x4{0.f, 0.f, 0.f, 0.f};
      oB[dt][jt] = oA[dt][jt];
    }
  {
    const f32x4* cmb4 = (const f32x4*)cmb;
    const long cbase = (long)(wA & 63) * 4096 + h * 1024 + lane;   // == wB's

#pragma unroll
    for (int jt = 0; jt < 4; ++jt) {
      f32x4 sA[4], sB[4];
#pragma unroll
      for (int i = 0; i < 4; ++i) {
        const f32x4 cv = cmb4[cbase + jt * 256 + i * 64];
        sA[i] = mfma16(kfrA[i], qfrA[jt], cv);
        sB[i] = mfma16(kfrB[i], qfrB[jt], cv);
      }

      float mxA = sA[0][0], mxB = sB[0][0];
#pragma unroll
      for (int i = 0; i < 4; ++i)
#pragma unroll
        for (int r = 0; r < 4; ++r) {
          mxA = fmaxf(mxA, sA[i][r]);
          mxB = fmaxf(mxB, sB[i][r]);
        }
      mxA = fmaxf(mxA, __shfl_xor(mxA, 16));
      mxB = fmaxf(mxB, __shfl_xor(mxB, 16));
      mxA = fmaxf(mxA, __shfl_xor(mxA, 32));
      mxB = fmaxf(mxB, __shfl_xor(mxB, 32));
      float sumA = 0.f, sumB = 0.f;
#pragma unroll
      for (int i = 0; i < 4; ++i)
#pragma unroll
        for (int r = 0; r < 4; ++r) {
          float eA = __expf(sA[i][r] - mxA);
          float eB = __expf(sB[i][r] - mxB);
          sA[i][r] = eA; sumA += eA;
          sB[i][r] = eB; sumB += eB;
        }
      sumA += __shfl_xor(sumA, 16);
      sumB += __shfl_xor(sumB, 16);
      sumA += __shfl_xor(sumA, 32);
      sumB += __shfl_xor(sumB, 32);
      const float invA = 1.f / sumA;
      const float invB = 1.f / sumB;

      short8v pbA[2], pbB[2];
#pragma unroll
      for (int ks = 0; ks < 2; ++ks) {
        short8v pvA, pvB;
#pragma unroll
        for (int e = 0; e < 4; ++e) {
          pvA[e]     = f2bf(sA[2 * ks][e] * invA);
          pvA[4 + e] = f2bf(sA[2 * ks + 1][e] * invA);
          pvB[e]     = f2bf(sB[2 * ks][e] * invB);
          pvB[4 + e] = f2bf(sB[2 * ks + 1][e] * invB);
        }
        pbA[ks] = pvA;
        pbB[ks] = pvB;
      }

#pragma unroll
      for (int dt = 0; dt < 2; ++dt)
#pragma unroll
        for (int ks = 0; ks < 2; ++ks) {
          const int va = h * 2176 + (dt * 16 + l15) * 68 + ks * 32 + lhi * 4;
          short8v vfA = cat44(*(const short4v*)&vtmA[va],
                              *(const short4v*)&vtmA[va + 16]);
          short8v vfB = cat44(*(const short4v*)&vtmB[va],
                              *(const short4v*)&vtmB[va + 16]);
          oA[dt][jt] = mfma16(vfA, pbA[ks], oA[dt][jt]);
          oB[dt][jt] = mfma16(vfB, pbB[ks], oB[dt][jt]);
        }
    }
  }
  __syncthreads();   // B2: all xb reads done; aomA/aomB may overwrite xbA/xbB

#pragma unroll
  for (int dt = 0; dt < 2; ++dt)
#pragma unroll
    for (int jt = 0; jt < 4; ++jt) {
      short4v pA, pB;
#pragma unroll
      for (int r = 0; r < 4; ++r) {
        pA[r] = f2bf(oA[dt][jt][r]);
        pB[r] = f2bf(oB[dt][jt][r]);
      }
      *(short4v*)&aomA[(jt * 16 + l15) * 136 + h * 32 + dt * 16 + lhi * 4] = pA;
      *(short4v*)&aomB[(jt * 16 + l15) * 136 + h * 32 + dt * 16 + lhi * 4] = pB;
    }
  __syncthreads();   // B3: aom complete

  // ---- Phase 3: output projection for BOTH windows (wfr shared).
  {
    f32x4 poA[2][4], poB[2][4];   // [nt][mt]
#pragma unroll
    for (int nt = 0; nt < 2; ++nt) {
      const float pbv = proj_b[h * 32 + nt * 16 + l15];
#pragma unroll
      for (int mt = 0; mt < 4; ++mt) {
        poA[nt][mt] = f32x4{pbv, pbv, pbv, pbv};
        poB[nt][mt] = poA[nt][mt];
      }
    }
#pragma unroll
    for (int ks = 0; ks < 4; ++ks) {
      short8v pA[4], pB[4];
#pragma unroll
      for (int mt = 0; mt < 4; ++mt) {
        pA[mt] = *(const short8v*)&aomA[(mt * 16 + l15) * 136 + ks * 32 + cb];
        pB[mt] = *(const short8v*)&aomB[(mt * 16 + l15) * 136 + ks * 32 + cb];
      }
#pragma unroll
      for (int nt = 0; nt < 2; ++nt) {
        const short8v wfr =
            *(const short8v*)&wp[(h * 32 + nt * 16 + l15) * 128 + ks * 32 + cb];
#pragma unroll
        for (int mt = 0; mt < 4; ++mt) {
          poA[nt][mt] = mfma16(pA[mt], wfr, poA[nt][mt]);
          poB[nt][mt] = mfma16(pB[mt], wfr, poB[nt][mt]);
        }
      }
    }
    float* outA = out + (long)wA * 6272;
    float* outB = out + (long)wB * 6272;
#pragma unroll
    for (int nt = 0; nt < 2; ++nt) {
      const int ncol = h * 32 + nt * 16 + l15;
#pragma unroll
      for (int mt = 0; mt < 4; ++mt)
#pragma unroll
        for (int r = 0; r < 4; ++r) {
          const int tok = mt * 16 + lhi * 4 + r;
          if (tok < 49) {
            outA[tok * 128 + ncol] = poA[nt][mt][r];
            outB[tok * 128 + ncol] = poB[nt][mt][r];
          }
        }
    }
  }
}

extern "C" void kernel_launch(void* const* d_in, const int* in_sizes, int n_in,
                              void* d_out, int out_size, void* d_ws, size_t ws_size,
                              hipStream_t stream) {
  const float* x          = (const float*)d_in[0];
  const float* mask       = (const float*)d_in[1];
  const float* qkv_w      = (const float*)d_in[2];
  const float* qkv_b      = (const float*)d_in[3];
  const float* proj_w     = (const float*)d_in[4];
  const float* proj_b     = (const float*)d_in[5];
  const float* bias_table = (const float*)d_in[6];

  short* wq  = (short*)d_ws;                         // 384*128 bf16 (98304 B)
  short* wp  = wq + 49152;                           // 128*128 bf16 (32768 B)
  float* cmb = (float*)((char*)d_ws + 131072);       // 4 MB combined bias+mask

  cvt_weights_kernel<<<dim3(192), dim3(256), 0, stream>>>(qkv_w, proj_w, wq, wp);
  build_cmb_kernel<<<dim3(1024), dim3(256), 0, stream>>>(mask, bias_table, cmb);
  win_attn_kernel<<<dim3(2048), dim3(256), 0, stream>>>(
      x, qkv_b, proj_b, wq, wp, cmb, (float*)d_out);
}

// Round 16
// 108.823 us; speedup vs baseline: 2.4038x; 1.8617x over previous
//
#include <hip/hip_runtime.h>
#include <stdint.h>

typedef float  f32x4   __attribute__((ext_vector_type(4)));
typedef float  float4v __attribute__((ext_vector_type(4)));
typedef short  short4v __attribute__((ext_vector_type(4)));
typedef short  short8v __attribute__((ext_vector_type(8)));
typedef __bf16 bf16x8  __attribute__((ext_vector_type(8)));

static __device__ __forceinline__ short f2bf(float f) {
  unsigned u = __builtin_bit_cast(unsigned, f);
  u += 0x7FFFu + ((u >> 16) & 1u);
  return (short)(u >> 16);
}

static __device__ __forceinline__ f32x4 mfma16(short8v a, short8v b, f32x4 c) {
  return __builtin_amdgcn_mfma_f32_16x16x32_bf16(
      __builtin_bit_cast(bf16x8, a), __builtin_bit_cast(bf16x8, b), c, 0, 0, 0);
}

static __device__ __forceinline__ short8v cat44(short4v a, short4v b) {
  short8v r;
  r[0] = a[0]; r[1] = a[1]; r[2] = a[2]; r[3] = a[3];
  r[4] = b[0]; r[5] = b[1]; r[6] = b[2]; r[7] = b[3];
  return r;
}

// Prelude A: convert qkv_w (384x128) and proj_w (128x128) f32 -> bf16.
__global__ void cvt_weights_kernel(const float* __restrict__ qkv_w,
                                   const float* __restrict__ proj_w,
                                   short* __restrict__ wq, short* __restrict__ wp) {
  int i = blockIdx.x * 256 + threadIdx.x;   // grid = 192 blocks -> 49152
  wq[i] = f2bf(qkv_w[i]);
  if (i < 16384) wp[i] = f2bf(proj_w[i]);
}

// Prelude B: combined bias+mask table laid out as the MFMA S-fragment:
// cmb[w(64)][h(4)][qt(4)][i(4)][lane(64)][r(4)] f32  (4 MB)
__global__ void build_cmb_kernel(const float* __restrict__ mask,
                                 const float* __restrict__ bias_table,
                                 float* __restrict__ cmb) {
  int id   = blockIdx.x * 256 + threadIdx.x;   // grid = 1024 blocks
  int lane = id & 63;
  int i    = (id >> 6) & 3;
  int qt   = (id >> 8) & 3;
  int h    = (id >> 10) & 3;
  int w    = id >> 12;
  int q     = qt * 16 + (lane & 15);
  int kbase = i * 16 + ((lane >> 4) << 2);
  f32x4 v;
#pragma unroll
  for (int r = 0; r < 4; ++r) {
    int key = kbase + r;
    float val;
    if (key >= 49) {
      val = -1e30f;
    } else if (q >= 49) {
      val = 0.f;
    } else {
      int qi = q / 7, qj = q - qi * 7;
      int ki = key / 7, kj = key - ki * 7;
      int ridx = (qi - ki + 6) * 13 + (qj - kj + 6);
      val = bias_table[ridx * 4 + h] + mask[w * 2401 + q * 49 + key];
    }
    v[r] = val;
  }
  ((f32x4*)cmb)[id] = v;
}

// One block = one window; 256 threads = 4 waves; wave = head h, ALL 64 tokens
// (the R12 champion structure: ~150 unified regs/wave, zero spill).
// R16 = R15 with the LDS overlap bug fixed: vtm is [4][32][68] = 8704 shorts
// ([8704,17408)), so aom starts at 17408 (R15 wrongly put it at 13056,
// clobbering vtm slices h=2,3 -> absmax 2.63 failure).
// LDS 52224 B; (256,3): 170-reg budget > ~150 demand, 3 blocks/CU
// (3*52224 = 156672 <= 163840). 2 barriers per window.
__global__ __launch_bounds__(256, 3)
void win_attn_kernel(const float* __restrict__ x,
                     const float* __restrict__ qkv_b,
                     const float* __restrict__ proj_b,
                     const short* __restrict__ wq,
                     const short* __restrict__ wp,
                     const float* __restrict__ cmb,
                     float* __restrict__ out) {
  __shared__ __align__(16) short smem[26112];   // 52224 B
  short* xb  = smem;            // [64][136]          [0, 8704)
  short* vtm = smem + 8704;     // [4][32][68] v^T    [8704, 17408)
  short* aom = smem + 17408;    // [64][136]          [17408, 26112)

  const int b    = blockIdx.x;
  const int tid  = threadIdx.x;
  const int lane = tid & 63;
  const int h    = tid >> 6;    // wave = head
  const int l15  = lane & 15;
  const int lhi  = lane >> 4;
  const int cb   = lhi * 8;

  // ---- Phase 0: stage x -> bf16 LDS, zero pad rows 49..63
  {
    short4v z = {0, 0, 0, 0};
    for (int idx = tid; idx < 510; idx += 256)
      *(short4v*)&xb[49 * 136 + idx * 4] = z;
    const float* xw = x + (long)b * (49 * 128);
    for (int idx = tid; idx < 1568; idx += 256) {
      int m  = idx >> 5;
      int c0 = (idx & 31) << 2;
      float4v v = *(const float4v*)&xw[m * 128 + c0];
      short4v s;
      s[0] = f2bf(v[0]); s[1] = f2bf(v[1]); s[2] = f2bf(v[2]); s[3] = f2bf(v[3]);
      *(short4v*)&xb[m * 136 + c0] = s;
    }
  }
  __syncthreads();   // B1

  // ---- Phase 1a: Q+K projection (swapped: acc = [wcol][token]), 64 tokens.
  short8v qfr[4], kfr[4];
  {
    f32x4 qa[2][4], ka[2][4];   // [nt][jt]
#pragma unroll
    for (int nt = 0; nt < 2; ++nt) {
      const f32x4 bq4 = *(const f32x4*)&qkv_b[h * 32 + nt * 16 + lhi * 4];
      const f32x4 bk4 = *(const f32x4*)&qkv_b[128 + h * 32 + nt * 16 + lhi * 4];
#pragma unroll
      for (int jt = 0; jt < 4; ++jt) { qa[nt][jt] = bq4; ka[nt][jt] = bk4; }
    }
#pragma unroll
    for (int ks = 0; ks < 4; ++ks) {
      short8v a[4];
#pragma unroll
      for (int jt = 0; jt < 4; ++jt)
        a[jt] = *(const short8v*)&xb[(jt * 16 + l15) * 136 + ks * 32 + cb];
#pragma unroll
      for (int nt = 0; nt < 2; ++nt) {
        const short8v bq =
            *(const short8v*)&wq[(h * 32 + nt * 16 + l15) * 128 + ks * 32 + cb];
        const short8v bk =
            *(const short8v*)&wq[(128 + h * 32 + nt * 16 + l15) * 128 + ks * 32 + cb];
#pragma unroll
        for (int jt = 0; jt < 4; ++jt) {
          qa[nt][jt] = mfma16(bq, a[jt], qa[nt][jt]);
          ka[nt][jt] = mfma16(bk, a[jt], ka[nt][jt]);
        }
      }
    }
    const float scale = 0.1767766952966369f;  // 32^-0.5
#pragma unroll
    for (int jt = 0; jt < 4; ++jt) {
      short8v qv, kv;
#pragma unroll
      for (int nt = 0; nt < 2; ++nt)
#pragma unroll
        for (int r = 0; r < 4; ++r) {
          qv[nt * 4 + r] = f2bf(qa[nt][jt][r] * scale);
          kv[nt * 4 + r] = f2bf(ka[nt][jt][r]);
        }
      qfr[jt] = qv;
      kfr[jt] = kv;
    }
  }

  // ---- Phase 1b: V projection (normal), store transposed to OWN vtm slice.
  {
    f32x4 va[2][4];   // [nt][mt]
#pragma unroll
    for (int nt = 0; nt < 2; ++nt) {
      const float vb = qkv_b[256 + h * 32 + nt * 16 + l15];
#pragma unroll
      for (int mt = 0; mt < 4; ++mt) va[nt][mt] = f32x4{vb, vb, vb, vb};
    }
#pragma unroll
    for (int ks = 0; ks < 4; ++ks) {
      short8v a[4];
#pragma unroll
      for (int mt = 0; mt < 4; ++mt)
        a[mt] = *(const short8v*)&xb[(mt * 16 + l15) * 136 + ks * 32 + cb];
#pragma unroll
      for (int nt = 0; nt < 2; ++nt) {
        const short8v bv =
            *(const short8v*)&wq[(256 + h * 32 + nt * 16 + l15) * 128 + ks * 32 + cb];
#pragma unroll
        for (int mt = 0; mt < 4; ++mt)
          va[nt][mt] = mfma16(a[mt], bv, va[nt][mt]);
      }
    }
#pragma unroll
    for (int nt = 0; nt < 2; ++nt)
#pragma unroll
      for (int mt = 0; mt < 4; ++mt) {
        short4v p;
#pragma unroll
        for (int r = 0; r < 4; ++r) p[r] = f2bf(va[nt][mt][r]);
        *(short4v*)&vtm[h * 2176 + (nt * 16 + l15) * 68 + mt * 16 + lhi * 4] = p;
      }
  }
  // vtm slice is private to this wave: in-wave lgkmcnt ordering suffices.

  // ---- Phase 2: S = mfma(K,Q) + cmb; in-lane softmax; PV -> aom directly.
  {
    const f32x4* cmb4 = (const f32x4*)cmb;
    const long cbase = (long)(b & 63) * 4096 + h * 1024 + lane;

#pragma unroll
    for (int jt = 0; jt < 4; ++jt) {
      f32x4 s[4];
#pragma unroll
      for (int i = 0; i < 4; ++i)
        s[i] = mfma16(kfr[i], qfr[jt], cmb4[cbase + jt * 256 + i * 64]);

      float mx = s[0][0];
#pragma unroll
      for (int i = 0; i < 4; ++i)
#pragma unroll
        for (int r = 0; r < 4; ++r) mx = fmaxf(mx, s[i][r]);
      mx = fmaxf(mx, __shfl_xor(mx, 16));
      mx = fmaxf(mx, __shfl_xor(mx, 32));
      float sum = 0.f;
#pragma unroll
      for (int i = 0; i < 4; ++i)
#pragma unroll
        for (int r = 0; r < 4; ++r) {
          float e = __expf(s[i][r] - mx);
          s[i][r] = e;
          sum += e;
        }
      sum += __shfl_xor(sum, 16);
      sum += __shfl_xor(sum, 32);
      const float inv = 1.f / sum;

      short8v pb[2];
#pragma unroll
      for (int ks = 0; ks < 2; ++ks) {
        short8v pv;
#pragma unroll
        for (int e = 0; e < 4; ++e) pv[e]     = f2bf(s[2 * ks][e] * inv);
#pragma unroll
        for (int e = 0; e < 4; ++e) pv[4 + e] = f2bf(s[2 * ks + 1][e] * inv);
        pb[ks] = pv;
      }

#pragma unroll
      for (int dt = 0; dt < 2; ++dt) {
        f32x4 o = {0.f, 0.f, 0.f, 0.f};
#pragma unroll
        for (int ks = 0; ks < 2; ++ks) {
          const int va = h * 2176 + (dt * 16 + l15) * 68 + ks * 32 + lhi * 4;
          short8v vfr = cat44(*(const short4v*)&vtm[va], *(const short4v*)&vtm[va + 16]);
          o = mfma16(vfr, pb[ks], o);
        }
        short4v p;
#pragma unroll
        for (int r = 0; r < 4; ++r) p[r] = f2bf(o[r]);
        *(short4v*)&aom[(jt * 16 + l15) * 136 + h * 32 + dt * 16 + lhi * 4] = p;
      }
    }
  }
  __syncthreads();   // B2: aom complete (all heads' columns visible)

  // ---- Phase 3: output projection Y = AO @ proj_w^T + proj_b (ks-outer)
  {
    f32x4 po[2][4];   // [nt][mt]
#pragma unroll
    for (int nt = 0; nt < 2; ++nt) {
      const float pbv = proj_b[h * 32 + nt * 16 + l15];
#pragma unroll
      for (int mt = 0; mt < 4; ++mt) po[nt][mt] = f32x4{pbv, pbv, pbv, pbv};
    }
#pragma unroll
    for (int ks = 0; ks < 4; ++ks) {
      short8v p[4];
#pragma unroll
      for (int mt = 0; mt < 4; ++mt)
        p[mt] = *(const short8v*)&aom[(mt * 16 + l15) * 136 + ks * 32 + cb];
#pragma unroll
      for (int nt = 0; nt < 2; ++nt) {
        const short8v wfr =
            *(const short8v*)&wp[(h * 32 + nt * 16 + l15) * 128 + ks * 32 + cb];
#pragma unroll
        for (int mt = 0; mt < 4; ++mt)
          po[nt][mt] = mfma16(p[mt], wfr, po[nt][mt]);
      }
    }
    float* outw = out + (long)b * (49 * 128);
#pragma unroll
    for (int nt = 0; nt < 2; ++nt) {
      const int ncol = h * 32 + nt * 16 + l15;
#pragma unroll
      for (int mt = 0; mt < 4; ++mt)
#pragma unroll
        for (int r = 0; r < 4; ++r) {
          const int m0 = mt * 16 + lhi * 4 + r;
          if (m0 < 49) outw[m0 * 128 + ncol] = po[nt][mt][r];
        }
    }
  }
}

extern "C" void kernel_launch(void* const* d_in, const int* in_sizes, int n_in,
                              void* d_out, int out_size, void* d_ws, size_t ws_size,
                              hipStream_t stream) {
  const float* x          = (const float*)d_in[0];
  const float* mask       = (const float*)d_in[1];
  const float* qkv_w      = (const float*)d_in[2];
  const float* qkv_b      = (const float*)d_in[3];
  const float* proj_w     = (const float*)d_in[4];
  const float* proj_b     = (const float*)d_in[5];
  const float* bias_table = (const float*)d_in[6];

  short* wq  = (short*)d_ws;                         // 384*128 bf16 (98304 B)
  short* wp  = wq + 49152;                           // 128*128 bf16 (32768 B)
  float* cmb = (float*)((char*)d_ws + 131072);       // 4 MB combined bias+mask

  cvt_weights_kernel<<<dim3(192), dim3(256), 0, stream>>>(qkv_w, proj_w, wq, wp);
  build_cmb_kernel<<<dim3(1024), dim3(256), 0, stream>>>(mask, bias_table, cmb);
  win_attn_kernel<<<dim3(4096), dim3(256), 0, stream>>>(
      x, qkv_b, proj_b, wq, wp, cmb, (float*)d_out);
}